// Round 3
// 566.380 us; speedup vs baseline: 1.0250x; 1.0250x over previous
//
#include <hip/hip_runtime.h>
#include <hip/hip_bf16.h>

#define NROW  64
#define KDIM  1024
#define NDIM  1024

typedef short bf16x8 __attribute__((ext_vector_type(8)));
typedef float f32x4  __attribute__((ext_vector_type(4)));

// fp32 -> bf16 round-half-up, two at once: (u + 0x8000) >> 16, packed with one v_perm_b32.
__device__ __forceinline__ unsigned pk2bf(float lo, float hi) {
  unsigned ulo = __builtin_bit_cast(unsigned, lo) + 0x8000u;
  unsigned uhi = __builtin_bit_cast(unsigned, hi) + 0x8000u;
  return __builtin_amdgcn_perm(uhi, ulo, 0x07060302u);
}

// out[m, r, n] = sum_k x[m, r, k] * W[r, k, n] + bias[r, n]
// per r: GEMM M=512 (batch), K=1024, N=1024.
// Block = 128x128 output tile, 256 threads (2x2 waves, each 64x64 via 4x4 MFMA 16x16x32 bf16).
// v2: (a) depth-2 pipeline with early bf16 convert -> barrier section is pure ds_write,
//     vmcnt wait moved into MFMA shadow, issue->use distance ~1 full iteration.
//     (b) B-staging lane remap so ds_write_b64 half-select alternates per lane (kills 4-way conflict).
//     (c) r-group-per-XCD swizzle: each XCD's W slice (32MB) + x slice (16.75MB) are exclusive.
__global__ __launch_bounds__(256) void Group_MLP_kernel(
    const float* __restrict__ x, const float* __restrict__ W,
    const float* __restrict__ bias, float* __restrict__ out) {
  // ---- block mapping: XCD gets r in [xcd*8, xcd*8+8); per r, 32 (mb,nb) blocks back-to-back.
  const int g   = blockIdx.x;
  const int xcd = g & 7;
  const int idx = g >> 3;          // 0..255 within XCD, dispatched in order
  const int r   = xcd * 8 + (idx >> 5);
  const int mb  = (idx >> 3) & 3;
  const int nb  = idx & 7;
  const int m0 = mb * 128;
  const int n0 = nb * 128;

  const int t    = threadIdx.x;
  const int l    = t & 63;
  const int wave = t >> 6;
  const int wm   = wave >> 1, wn = wave & 1;
  const int lm   = l & 15, quad = l >> 4;

  // LDS: fragment-linear chunks of 16 B.
  // A region: logical chunk p = mt*64 + q*16 + lm  holds  x[m0 + mt*16 + lm][k0 + q*8 .. +7]
  // B region: logical chunk p = nt*64 + quad*16 + lm holds W[k0 + quad*8 .. +7][n0 + nt*16 + lm]
  //           stored at PHYSICAL chunk p ^ ((p>>6)&7)  (XOR swizzle)
  __shared__ uint4 smem4[1024];   // 16 KiB: A = [0,512), B = [512,1024)
  uint2* s2 = (uint2*)smem4;      // 8 B half-chunks

  // ---- A staging: half-chunk index c = i*256 + t; gA[i] = gA0 + i*32 rows
  // ma = (i*2 + (t>>7))*16 + ((t>>1)&15), kof independent of i.
  const int maBase = ((t >> 7) << 4) | ((t >> 1) & 15);
  const int kof    = (((t >> 5) & 3) << 3) | ((t & 1) << 2);
  const float* gA0 = x + (size_t)(m0 + maBase) * (NROW * KDIM) + r * KDIM + kof;
  const size_t ASTRIDE = (size_t)32 * (NROW * KDIM);   // +32 rows in m

  // ---- B staging: thread (n4,qh) loads W[qh*4+j][n0+n4*4 .. +3], j=0..3; register 4x4 transpose.
  // Lane remap: hB = qh&1 = t&1 alternates within each half-wave -> conflict-free ds_write_b64.
  const int n4 = (t >> 1) & 31;
  const int qh = (t & 1) | ((t >> 6) << 1);
  const float* gB = W + (size_t)r * (KDIM * NDIM) + (qh * 4) * NDIM + n0 + n4 * 4;
  const int baseP  = (n4 >> 2) * 64 + ((qh >> 1) & 3) * 16 + (n4 & 3) * 4;
  const int swBase = baseP ^ (n4 >> 2);        // XOR swizzle ((p>>6)&7 == n4>>2, c-independent)
  const int hB     = qh & 1;                   // which 8B half of the 16B chunk
  const int bW     = 1024 | (swBase << 1) | hB; // half-chunk addr; chunk c at bW ^ (c<<1)

  // ---- fragment read indices (16 B physical chunk units)
  int aIdx[4], bIdx[4];
  #pragma unroll
  for (int i = 0; i < 4; ++i) aIdx[i] = (wm * 4 + i) * 64 + l;
  #pragma unroll
  for (int j = 0; j < 4; ++j) {
    int grp = wn * 4 + j;
    bIdx[j] = 512 + grp * 64 + (l ^ grp);      // physical chunk of logical grp*64 + l
  }

  f32x4 acc[4][4];
  #pragma unroll
  for (int i = 0; i < 4; ++i)
    #pragma unroll
    for (int j = 0; j < 4; ++j)
      acc[i][j] = {0.f, 0.f, 0.f, 0.f};

  float4 rawA[4], rawB[4];   // slab ks+1, fp32 in flight
  uint2  cvtA[4], cvtB[4];   // slab ks, bf16 ready to write

  // ---- prologue: load slab 0, convert it, issue slab 1
  #pragma unroll
  for (int i = 0; i < 4; ++i) rawA[i] = *(const float4*)(gA0 + i * ASTRIDE);
  #pragma unroll
  for (int j = 0; j < 4; ++j) rawB[j] = *(const float4*)(gB + j * NDIM);

  #pragma unroll
  for (int i = 0; i < 4; ++i) {
    cvtA[i].x = pk2bf(rawA[i].x, rawA[i].y);
    cvtA[i].y = pk2bf(rawA[i].z, rawA[i].w);
  }
  cvtB[0].x = pk2bf(rawB[0].x, rawB[1].x); cvtB[0].y = pk2bf(rawB[2].x, rawB[3].x);
  cvtB[1].x = pk2bf(rawB[0].y, rawB[1].y); cvtB[1].y = pk2bf(rawB[2].y, rawB[3].y);
  cvtB[2].x = pk2bf(rawB[0].z, rawB[1].z); cvtB[2].y = pk2bf(rawB[2].z, rawB[3].z);
  cvtB[3].x = pk2bf(rawB[0].w, rawB[1].w); cvtB[3].y = pk2bf(rawB[2].w, rawB[3].w);

  gA0 += 32;
  gB  += 32 * NDIM;
  #pragma unroll
  for (int i = 0; i < 4; ++i) rawA[i] = *(const float4*)(gA0 + i * ASTRIDE);
  #pragma unroll
  for (int j = 0; j < 4; ++j) rawB[j] = *(const float4*)(gB + j * NDIM);

  for (int ks = 0; ks < 32; ++ks) {
    __syncthreads();   // previous iteration's LDS reads done
    // ---- barrier-critical section: pure register -> LDS writes (no waits, no VALU convert)
    #pragma unroll
    for (int i = 0; i < 4; ++i) s2[i * 256 + t] = cvtA[i];
    #pragma unroll
    for (int c = 0; c < 4; ++c) s2[bW ^ (c << 1)] = cvtB[c];
    __syncthreads();

    // ---- compute tail: ds_read fragments, then (convert slab ks+1, issue slab ks+2) under MFMA
    bf16x8 af[4], bfr[4];
    #pragma unroll
    for (int i = 0; i < 4; ++i) af[i]  = __builtin_bit_cast(bf16x8, smem4[aIdx[i]]);
    #pragma unroll
    for (int j = 0; j < 4; ++j) bfr[j] = __builtin_bit_cast(bf16x8, smem4[bIdx[j]]);

    if (ks < 31) {
      // convert slab ks+1 (this is where the vmcnt wait lands, overlapped with lgkm/MFMA)
      #pragma unroll
      for (int i = 0; i < 4; ++i) {
        cvtA[i].x = pk2bf(rawA[i].x, rawA[i].y);
        cvtA[i].y = pk2bf(rawA[i].z, rawA[i].w);
      }
      cvtB[0].x = pk2bf(rawB[0].x, rawB[1].x); cvtB[0].y = pk2bf(rawB[2].x, rawB[3].x);
      cvtB[1].x = pk2bf(rawB[0].y, rawB[1].y); cvtB[1].y = pk2bf(rawB[2].y, rawB[3].y);
      cvtB[2].x = pk2bf(rawB[0].z, rawB[1].z); cvtB[2].y = pk2bf(rawB[2].z, rawB[3].z);
      cvtB[3].x = pk2bf(rawB[0].w, rawB[1].w); cvtB[3].y = pk2bf(rawB[2].w, rawB[3].w);
      if (ks < 30) {
        gA0 += 32;
        gB  += 32 * NDIM;
        #pragma unroll
        for (int i = 0; i < 4; ++i) rawA[i] = *(const float4*)(gA0 + i * ASTRIDE);
        #pragma unroll
        for (int j = 0; j < 4; ++j) rawB[j] = *(const float4*)(gB + j * NDIM);
      }
    }

    #pragma unroll
    for (int i = 0; i < 4; ++i)
      #pragma unroll
      for (int j = 0; j < 4; ++j)
        acc[i][j] = __builtin_amdgcn_mfma_f32_16x16x32_bf16(af[i], bfr[j], acc[i][j], 0, 0, 0);
  }

  // ---- epilogue: C/D layout col = lane&15, row = quad*4 + reg
  const int nColBase = n0 + wn * 64 + lm;
  const int mRowBase = m0 + wm * 64 + quad * 4;
  #pragma unroll
  for (int j = 0; j < 4; ++j) {
    int n = nColBase + j * 16;
    float bv = bias[r * NDIM + n];
    #pragma unroll
    for (int i = 0; i < 4; ++i) {
      int mr = mRowBase + i * 16;
      #pragma unroll
      for (int v = 0; v < 4; ++v) {
        out[(size_t)(mr + v) * (NROW * NDIM) + r * NDIM + n] = acc[i][j][v] + bv;
      }
    }
  }
}

extern "C" void kernel_launch(void* const* d_in, const int* in_sizes, int n_in,
                              void* d_out, int out_size, void* d_ws, size_t ws_size,
                              hipStream_t stream) {
  const float* x    = (const float*)d_in[0];
  const float* W    = (const float*)d_in[1];
  const float* bias = (const float*)d_in[2];
  float* out        = (float*)d_out;
  dim3 grid(64 * 4 * 8), block(256);
  hipLaunchKernelGGL(Group_MLP_kernel, grid, block, 0, stream, x, W, bias, out);
}

// Round 4
// 513.150 us; speedup vs baseline: 1.1313x; 1.1037x over previous
//
#include <hip/hip_runtime.h>
#include <hip/hip_bf16.h>

#define NROW  64
#define KDIM  1024
#define NDIM  1024

typedef short bf16x8 __attribute__((ext_vector_type(8)));
typedef float f32x4  __attribute__((ext_vector_type(4)));

// fp32 -> bf16 round-half-up, two at once: (u + 0x8000) >> 16, packed with one v_perm_b32.
__device__ __forceinline__ unsigned pk2bf(float lo, float hi) {
  unsigned ulo = __builtin_bit_cast(unsigned, lo) + 0x8000u;
  unsigned uhi = __builtin_bit_cast(unsigned, hi) + 0x8000u;
  return __builtin_amdgcn_perm(uhi, ulo, 0x07060302u);
}

// out[m, r, n] = sum_k x[m, r, k] * W[r, k, n] + bias[r, n]
// per r: GEMM M=512 (batch), K=1024, N=1024.
// v3: 256x256 tile, 512 threads (2x4 waves, wave tile 128x64 via 8x4 MFMA 16x16x32 bf16).
//     Halves L2-miss traffic vs 128^2 (x re-read x4 not x8, W x2 not x4); 64 MFMA/wave/K-step
//     amortizes load latency 4x better. Depth-2 reg pipeline (early convert) retained.
//     B-write lane map now bank-PAIR-bijective within fixed 16-lane hw groups
//     (round-3 counter was exactly 4*4*4*32*2048: pair bit2 was t4, constant per group).
__global__ __launch_bounds__(512, 2) void Group_MLP_kernel(
    const float* __restrict__ x, const float* __restrict__ W,
    const float* __restrict__ bias, float* __restrict__ out) {
  // ---- block mapping: 512 blocks; XCD gets r in [xcd*8, xcd*8+8); 8 blocks per r.
  const int g   = blockIdx.x;
  const int xcd = g & 7;
  const int idx = g >> 3;          // 0..63
  const int r   = xcd * 8 + (idx >> 3);
  const int mb  = (idx >> 2) & 1;  // 0..1
  const int nb  = idx & 3;         // 0..3
  const int m0 = mb * 256;
  const int n0 = nb * 256;

  const int t    = threadIdx.x;    // 0..511
  const int l    = t & 63;
  const int wave = t >> 6;         // 0..7
  const int wm   = wave >> 2, wn = wave & 3;   // 2 x 4 -> wave tile 128m x 64n
  const int lm   = l & 15, quad = l >> 4;

  // LDS: fragment-linear 16 B chunks.
  // A chunk p = mt*64 + q*16 + lm  holds  x[m0 + mt*16 + lm][k0 + q*8 .. +7]   (mt 0..15)
  // B chunk p = nt*64 + quad*16 + lm holds W[k0 + quad*8 .. +7][n0 + nt*16 + lm] (nt 0..15)
  //   stored at PHYSICAL chunk p ^ ((p>>6)&7)
  __shared__ uint4 smem4[2048];   // 32 KiB: A = [0,1024), B = [1024,2048)
  uint2* s2 = (uint2*)smem4;      // 8 B half-chunks

  // ---- A staging: half-chunk c = i*512 + t, i = 0..3 (rows m0 + i*64 + maBase)
  const int maBase = ((t >> 7) << 4) | ((t >> 1) & 15);            // 0..63
  const int kof    = (((t >> 5) & 3) << 3) | ((t & 1) << 2);       // 0..28
  const float* gA[4];
  #pragma unroll
  for (int i = 0; i < 4; ++i)
    gA[i] = x + (size_t)(m0 + i * 64 + maBase) * (NROW * KDIM) + r * KDIM + kof;

  // ---- B staging: thread (n4 in 0..63, qh in 0..7) loads W[qh*4+j][n0+n4*4 .. +3], j=0..3.
  // Lane-bit map (bank-pair = (n4_0^n4_4, n4_3, n4_2, qh_0), must biject t3..t0 per 16-lane group):
  //   qh_0=t0, n4_2=t1, n4_3=t2, n4_0=t3, n4_4=t4, n4_1=t5, n4_5=t6, qh_1=t7, qh_2=t8.
  // Coalescing: per fixed qh, n4 covers a contiguous 32-value range -> 512 B segments.
  const int n4 = ((t >> 3) & 1) | (((t >> 5) & 1) << 1) | (((t >> 1) & 1) << 2)
               | (((t >> 2) & 1) << 3) | (((t >> 4) & 1) << 4) | (((t >> 6) & 1) << 5);
  const int qh = (t & 1) | (((t >> 7) & 1) << 1) | (((t >> 8) & 1) << 2);
  const float* gB[4];
  #pragma unroll
  for (int j = 0; j < 4; ++j)
    gB[j] = W + (size_t)r * (KDIM * NDIM) + (qh * 4 + j) * NDIM + n0 + n4 * 4;
  const int baseP  = (n4 >> 2) * 64 + ((qh >> 1) & 3) * 16 + (n4 & 3) * 4;
  const int swBase = baseP ^ ((n4 >> 2) & 7);   // XOR swizzle, cc-independent (no carry: baseP&63<=60)
  const int hB     = qh & 1;                    // which 8B half of the 16B chunk
  const int bW     = 2048 | (swBase << 1) | hB; // half-chunk addr; chunk cc at bW ^ (cc<<1)

  // ---- fragment read indices (16 B physical chunk units)
  int aIdx[8], bIdx[4];
  #pragma unroll
  for (int i = 0; i < 8; ++i) aIdx[i] = (wm * 8 + i) * 64 + l;
  #pragma unroll
  for (int j = 0; j < 4; ++j) {
    int grp = wn * 4 + j;                        // 0..15
    bIdx[j] = 1024 + grp * 64 + (l ^ (grp & 7)); // physical chunk of logical grp*64 + l
  }

  f32x4 acc[8][4];
  #pragma unroll
  for (int i = 0; i < 8; ++i)
    #pragma unroll
    for (int j = 0; j < 4; ++j)
      acc[i][j] = {0.f, 0.f, 0.f, 0.f};

  float4 rawA[4], rawB[4];   // slab ks+1, fp32 in flight
  uint2  cvtA[4], cvtB[4];   // slab ks, bf16 ready to write

  // ---- prologue: load slab 0, convert it, issue slab 1
  #pragma unroll
  for (int i = 0; i < 4; ++i) rawA[i] = *(const float4*)(gA[i]);
  #pragma unroll
  for (int j = 0; j < 4; ++j) rawB[j] = *(const float4*)(gB[j]);

  #pragma unroll
  for (int i = 0; i < 4; ++i) {
    cvtA[i].x = pk2bf(rawA[i].x, rawA[i].y);
    cvtA[i].y = pk2bf(rawA[i].z, rawA[i].w);
  }
  cvtB[0].x = pk2bf(rawB[0].x, rawB[1].x); cvtB[0].y = pk2bf(rawB[2].x, rawB[3].x);
  cvtB[1].x = pk2bf(rawB[0].y, rawB[1].y); cvtB[1].y = pk2bf(rawB[2].y, rawB[3].y);
  cvtB[2].x = pk2bf(rawB[0].z, rawB[1].z); cvtB[2].y = pk2bf(rawB[2].z, rawB[3].z);
  cvtB[3].x = pk2bf(rawB[0].w, rawB[1].w); cvtB[3].y = pk2bf(rawB[2].w, rawB[3].w);

  #pragma unroll
  for (int i = 0; i < 4; ++i) { gA[i] += 32; rawA[i] = *(const float4*)(gA[i]); }
  #pragma unroll
  for (int j = 0; j < 4; ++j) { gB[j] += 32 * NDIM; rawB[j] = *(const float4*)(gB[j]); }

  for (int ks = 0; ks < 32; ++ks) {
    __syncthreads();   // previous iteration's LDS reads done
    // ---- barrier-critical section: pure register -> LDS writes
    #pragma unroll
    for (int i = 0; i < 4; ++i) s2[i * 512 + t] = cvtA[i];
    #pragma unroll
    for (int cc = 0; cc < 4; ++cc) s2[bW ^ (cc << 1)] = cvtB[cc];
    __syncthreads();

    // ---- ds_read fragments, then (convert slab ks+1, issue slab ks+2) under MFMA
    bf16x8 af[8], bfr[4];
    #pragma unroll
    for (int i = 0; i < 8; ++i) af[i]  = __builtin_bit_cast(bf16x8, smem4[aIdx[i]]);
    #pragma unroll
    for (int j = 0; j < 4; ++j) bfr[j] = __builtin_bit_cast(bf16x8, smem4[bIdx[j]]);

    if (ks < 31) {
      #pragma unroll
      for (int i = 0; i < 4; ++i) {
        cvtA[i].x = pk2bf(rawA[i].x, rawA[i].y);
        cvtA[i].y = pk2bf(rawA[i].z, rawA[i].w);
      }
      cvtB[0].x = pk2bf(rawB[0].x, rawB[1].x); cvtB[0].y = pk2bf(rawB[2].x, rawB[3].x);
      cvtB[1].x = pk2bf(rawB[0].y, rawB[1].y); cvtB[1].y = pk2bf(rawB[2].y, rawB[3].y);
      cvtB[2].x = pk2bf(rawB[0].z, rawB[1].z); cvtB[2].y = pk2bf(rawB[2].z, rawB[3].z);
      cvtB[3].x = pk2bf(rawB[0].w, rawB[1].w); cvtB[3].y = pk2bf(rawB[2].w, rawB[3].w);
      if (ks < 30) {
        #pragma unroll
        for (int i = 0; i < 4; ++i) { gA[i] += 32; rawA[i] = *(const float4*)(gA[i]); }
        #pragma unroll
        for (int j = 0; j < 4; ++j) { gB[j] += 32 * NDIM; rawB[j] = *(const float4*)(gB[j]); }
      }
    }

    #pragma unroll
    for (int j = 0; j < 4; ++j)
      #pragma unroll
      for (int i = 0; i < 8; ++i)
        acc[i][j] = __builtin_amdgcn_mfma_f32_16x16x32_bf16(af[i], bfr[j], acc[i][j], 0, 0, 0);
  }

  // ---- epilogue: C/D layout col = lane&15, row = quad*4 + reg
  const int nColBase = n0 + wn * 64 + lm;
  const int mRowBase = m0 + wm * 128 + quad * 4;
  #pragma unroll
  for (int j = 0; j < 4; ++j) {
    int n = nColBase + j * 16;
    float bv = bias[r * NDIM + n];
    #pragma unroll
    for (int i = 0; i < 8; ++i) {
      int mr = mRowBase + i * 16;
      #pragma unroll
      for (int v = 0; v < 4; ++v) {
        out[(size_t)(mr + v) * (NROW * NDIM) + r * NDIM + n] = acc[i][j][v] + bv;
      }
    }
  }
}

extern "C" void kernel_launch(void* const* d_in, const int* in_sizes, int n_in,
                              void* d_out, int out_size, void* d_ws, size_t ws_size,
                              hipStream_t stream) {
  const float* x    = (const float*)d_in[0];
  const float* W    = (const float*)d_in[1];
  const float* bias = (const float*)d_in[2];
  float* out        = (float*)d_out;
  dim3 grid(512), block(512);
  hipLaunchKernelGGL(Group_MLP_kernel, grid, block, 0, stream, x, W, bias, out);
}